// Round 1
// baseline (5602.486 us; speedup 1.0000x reference)
//
#include <hip/hip_runtime.h>
#include <hip/hip_bf16.h>

#define EPS_RMS 1.1920929e-07f

constexpr int B_ = 2, S_ = 2048, D_ = 1024, H_ = 16, HD_ = 64, SD_ = 64;
constexpr int M_ = B_ * S_;      // 4096 rows
constexpr int D3_ = 3 * D_;      // 3072

// ---------------- FiLM modulation: state_mod = state @ w_state_mod ----------------
// fg[b,d] = gamma[d]*(1+sm[b,d]); fb[b,d] = beta[d]+sm[b,D+d]
__global__ void film_kernel(const float* __restrict__ state,
                            const float* __restrict__ w_sm,
                            const float* __restrict__ gamma,
                            const float* __restrict__ beta,
                            float* __restrict__ fg, float* __restrict__ fb) {
  int c = blockIdx.x * 256 + threadIdx.x;   // 0..2047
  int b = blockIdx.y;
  float acc = 0.f;
#pragma unroll 8
  for (int k = 0; k < SD_; ++k)
    acc += state[b * SD_ + k] * w_sm[k * (2 * D_) + c];
  if (c < D_) fg[b * D_ + c] = gamma[c] * (1.f + acc);
  else        fb[b * D_ + (c - D_)] = beta[c - D_] + acc;
}

// ---------------- RMSNorm + FiLM: h = rmsnorm(x)*nw*fg + fb ----------------
__global__ __launch_bounds__(256) void rmsnorm_film_kernel(
    const float* __restrict__ X, const float* __restrict__ nw,
    const float* __restrict__ fg, const float* __restrict__ fb,
    float* __restrict__ Hout) {
  int row = blockIdx.x;            // 0..4095
  int b = row / S_;
  int t = threadIdx.x;
  const float4* x4 = (const float4*)(X + (size_t)row * D_);
  float4 xv = x4[t];
  float ss = xv.x * xv.x + xv.y * xv.y + xv.z * xv.z + xv.w * xv.w;
#pragma unroll
  for (int off = 32; off >= 1; off >>= 1) ss += __shfl_xor(ss, off);
  __shared__ float red[4];
  if ((t & 63) == 0) red[t >> 6] = ss;
  __syncthreads();
  float tot = red[0] + red[1] + red[2] + red[3];
  float scale = rsqrtf(tot / (float)D_ + EPS_RMS);
  int d = t * 4;
  const float4 nw4 = *(const float4*)(nw + d);
  const float4 g4  = *(const float4*)(fg + b * D_ + d);
  const float4 b4  = *(const float4*)(fb + b * D_ + d);
  float4 hv;
  hv.x = xv.x * scale * nw4.x * g4.x + b4.x;
  hv.y = xv.y * scale * nw4.y * g4.y + b4.y;
  hv.z = xv.z * scale * nw4.z * g4.z + b4.z;
  hv.w = xv.w * scale * nw4.w * g4.w + b4.w;
  ((float4*)(Hout + (size_t)row * D_))[t] = hv;
}

// ---------------- f32 GEMM: C = A(MxK) @ B(KxN), 128x128x8 tile ----------------
// EPI: 0 = store, 1 = silu(acc), 2 = C *= acc (read-modify), 3 = C = Res + acc
template<int EPI>
__global__ __launch_bounds__(256) void gemm128(
    const float* __restrict__ A, const float* __restrict__ Bw,
    const float* __restrict__ Res, float* __restrict__ C,
    int M, int N, int K) {
  __shared__ float As[8][128];
  __shared__ float Bs[8][128];
  int t = threadIdx.x;
  int bm = blockIdx.y * 128, bn = blockIdx.x * 128;
  int ar = t >> 1, ac = (t & 1) * 4;       // A tile: 128 rows x 8 k
  int br = t >> 5, bc = (t & 31) * 4;      // B tile: 8 k x 128 cols
  int ty = t >> 4, tx = t & 15;            // 8x8 microtile
  float acc[8][8];
#pragma unroll
  for (int i = 0; i < 8; ++i)
#pragma unroll
    for (int j = 0; j < 8; ++j) acc[i][j] = 0.f;

  for (int k0 = 0; k0 < K; k0 += 8) {
    float4 av = *(const float4*)(A + (size_t)(bm + ar) * K + k0 + ac);
    float4 bv = *(const float4*)(Bw + (size_t)(k0 + br) * N + bn + bc);
    As[ac + 0][ar] = av.x; As[ac + 1][ar] = av.y;
    As[ac + 2][ar] = av.z; As[ac + 3][ar] = av.w;
    *(float4*)&Bs[br][bc] = bv;
    __syncthreads();
#pragma unroll
    for (int k = 0; k < 8; ++k) {
      float a[8], bb[8];
      *(float4*)&a[0]  = *(const float4*)&As[k][ty * 8];
      *(float4*)&a[4]  = *(const float4*)&As[k][ty * 8 + 4];
      *(float4*)&bb[0] = *(const float4*)&Bs[k][tx * 8];
      *(float4*)&bb[4] = *(const float4*)&Bs[k][tx * 8 + 4];
#pragma unroll
      for (int i = 0; i < 8; ++i)
#pragma unroll
        for (int j = 0; j < 8; ++j) acc[i][j] += a[i] * bb[j];
    }
    __syncthreads();
  }

#pragma unroll
  for (int i = 0; i < 8; ++i) {
    size_t base = (size_t)(bm + ty * 8 + i) * (size_t)N + bn + tx * 8;
    float vals[8];
#pragma unroll
    for (int j = 0; j < 8; ++j) vals[j] = acc[i][j];
    if constexpr (EPI == 1) {
#pragma unroll
      for (int j = 0; j < 8; ++j) vals[j] = vals[j] / (1.f + __expf(-vals[j]));
    } else if constexpr (EPI == 2) {
      float4 c0 = *(const float4*)(C + base);
      float4 c1 = *(const float4*)(C + base + 4);
      vals[0] *= c0.x; vals[1] *= c0.y; vals[2] *= c0.z; vals[3] *= c0.w;
      vals[4] *= c1.x; vals[5] *= c1.y; vals[6] *= c1.z; vals[7] *= c1.w;
    } else if constexpr (EPI == 3) {
      float4 r0 = *(const float4*)(Res + base);
      float4 r1 = *(const float4*)(Res + base + 4);
      vals[0] += r0.x; vals[1] += r0.y; vals[2] += r0.z; vals[3] += r0.w;
      vals[4] += r1.x; vals[5] += r1.y; vals[6] += r1.z; vals[7] += r1.w;
    }
    float4 o0 = {vals[0], vals[1], vals[2], vals[3]};
    float4 o1 = {vals[4], vals[5], vals[6], vals[7]};
    *(float4*)(C + base) = o0;
    *(float4*)(C + base + 4) = o1;
  }
}

// ---------------- causal flash attention, 1 wave per query row ----------------
__global__ __launch_bounds__(256) void attn_kernel(
    const float* __restrict__ qkv, float* __restrict__ AO) {
  int w = blockIdx.x * 4 + (threadIdx.x >> 6);
  int lane = threadIdx.x & 63;
  int sq = w % S_;
  int h = (w / S_) % H_;
  int b = w / (S_ * H_);
  const float* qptr = qkv + ((size_t)(b * S_ + sq) * 3 + 0) * D_ + h * HD_;
  float q[64];
#pragma unroll
  for (int i = 0; i < 16; ++i) {
    float4 v = ((const float4*)qptr)[i];
    q[4 * i] = v.x; q[4 * i + 1] = v.y; q[4 * i + 2] = v.z; q[4 * i + 3] = v.w;
  }
  float o[64];
#pragma unroll
  for (int i = 0; i < 64; ++i) o[i] = 0.f;
  float m = -INFINITY, l = 0.f;
  const float scale = 0.125f;  // 1/sqrt(64)

  for (int kt = 0; kt <= sq; kt += 64) {
    int kidx = kt + lane;
    bool valid = kidx <= sq;
    const float* kptr = qkv + ((size_t)(b * S_ + kidx) * 3 + 1) * D_ + h * HD_;
    float s = 0.f;
#pragma unroll
    for (int i = 0; i < 16; ++i) {
      float4 kv = ((const float4*)kptr)[i];
      s += q[4 * i] * kv.x + q[4 * i + 1] * kv.y + q[4 * i + 2] * kv.z + q[4 * i + 3] * kv.w;
    }
    float sv = valid ? s * scale : -INFINITY;
    float mt = sv;
#pragma unroll
    for (int off = 32; off >= 1; off >>= 1) mt = fmaxf(mt, __shfl_xor(mt, off));
    float mnew = fmaxf(m, mt);
    float corr = __expf(m - mnew);     // m=-inf first iter -> 0
    float p = __expf(sv - mnew);       // -inf -> 0 for invalid lanes
    l = l * corr + p;
    const float* vptr = qkv + ((size_t)(b * S_ + kidx) * 3 + 2) * D_ + h * HD_;
#pragma unroll
    for (int i = 0; i < 16; ++i) {
      float4 vv = ((const float4*)vptr)[i];
      o[4 * i]     = o[4 * i]     * corr + p * vv.x;
      o[4 * i + 1] = o[4 * i + 1] * corr + p * vv.y;
      o[4 * i + 2] = o[4 * i + 2] * corr + p * vv.z;
      o[4 * i + 3] = o[4 * i + 3] * corr + p * vv.w;
    }
    m = mnew;
  }
#pragma unroll
  for (int off = 32; off >= 1; off >>= 1) l += __shfl_xor(l, off);
  float res = 0.f;
#pragma unroll
  for (int d = 0; d < 64; ++d) {
    float v = o[d];
#pragma unroll
    for (int off = 32; off >= 1; off >>= 1) v += __shfl_xor(v, off);
    res = (lane == d) ? v : res;
  }
  AO[(size_t)(b * S_ + sq) * D_ + h * HD_ + lane] = res / l;
}

// ---------------- column mean over S (two stage) ----------------
__global__ void colmean1(const float* __restrict__ X, float* __restrict__ part) {
  int d = blockIdx.x * 256 + threadIdx.x;  // 0..1023
  int b = blockIdx.y;
  int ch = blockIdx.z;                     // 0..15
  float s = 0.f;
  int s0 = ch * (S_ / 16);
  for (int i = 0; i < S_ / 16; ++i)
    s += X[(size_t)(b * S_ + s0 + i) * D_ + d];
  part[(b * 16 + ch) * D_ + d] = s;
}
__global__ void colmean2(const float* __restrict__ part, float* __restrict__ cm) {
  int d = blockIdx.x * 256 + threadIdx.x;
  int b = blockIdx.y;
  float s = 0.f;
#pragma unroll
  for (int c = 0; c < 16; ++c) s += part[(b * 16 + c) * D_ + d];
  cm[b * D_ + d] = s * (1.f / (float)S_);
}

// ---------------- recurrent state update ----------------
__global__ __launch_bounds__(128) void state_kernel(
    const float* __restrict__ cm, const float* __restrict__ state,
    const float* __restrict__ w_h2s, const float* __restrict__ w_sg,
    float* __restrict__ out_tail) {
  int t = threadIdx.x;        // 0..127
  int b = t >> 6, j = t & 63;
  float ni = 0.f;
  for (int k = 0; k < D_; ++k) ni += cm[b * D_ + k] * w_h2s[k * SD_ + j];
  __shared__ float ni_s[128];
  ni_s[t] = ni;
  __syncthreads();
  float g = 0.f;
#pragma unroll
  for (int k = 0; k < SD_; ++k) g += state[b * SD_ + k] * w_sg[k * SD_ + j];
#pragma unroll
  for (int k = 0; k < SD_; ++k) g += ni_s[b * SD_ + k] * w_sg[(SD_ + k) * SD_ + j];
  g = 1.f / (1.f + __expf(-g));
  float st = state[b * SD_ + j];
  out_tail[b * SD_ + j] = st * (1.f - g) + ni * g;
}

extern "C" void kernel_launch(void* const* d_in, const int* in_sizes, int n_in,
                              void* d_out, int out_size, void* d_ws, size_t ws_size,
                              hipStream_t stream) {
  const float* x      = (const float*)d_in[0];
  const float* gamma  = (const float*)d_in[1];
  const float* beta   = (const float*)d_in[2];
  const float* state  = (const float*)d_in[3];
  const float* w_qkv  = (const float*)d_in[4];
  const float* w_o    = (const float*)d_in[5];
  const float* w_gate = (const float*)d_in[6];
  const float* w_up   = (const float*)d_in[7];
  const float* w_down = (const float*)d_in[8];
  const float* norm1w = (const float*)d_in[9];
  const float* norm2w = (const float*)d_in[10];
  const float* w_sm   = (const float*)d_in[11];
  const float* w_h2s  = (const float*)d_in[12];
  const float* w_sg   = (const float*)d_in[13];
  float* out = (float*)d_out;

  float* ws   = (float*)d_ws;
  float* fg   = ws;                  // 2048
  float* fb   = ws + 2048;           // 2048
  float* cm   = ws + 4096;           // 2048
  float* part = ws + 8192;           // 32768
  float* bufH   = ws + 65536;                      // 4M floats (h / attn_out / h2)
  float* bufQKV = ws + 65536 + (size_t)M_ * D_;    // 12M floats (qkv / gate*up)

  // 1. FiLM params
  film_kernel<<<dim3(8, B_), 256, 0, stream>>>(state, w_sm, gamma, beta, fg, fb);
  // 2. h = rmsnorm(x,norm1)*fg + fb
  rmsnorm_film_kernel<<<M_, 256, 0, stream>>>(x, norm1w, fg, fb, bufH);
  // 3. qkv = h @ w_qkv
  gemm128<0><<<dim3(D3_ / 128, M_ / 128), 256, 0, stream>>>(bufH, w_qkv, nullptr, bufQKV, M_, D3_, D_);
  // 4. attention -> bufH (h is dead)
  attn_kernel<<<(B_ * H_ * S_) / 4, 256, 0, stream>>>(bufQKV, bufH);
  // 5. x1 = x + AO @ w_o -> d_out
  gemm128<3><<<dim3(D_ / 128, M_ / 128), 256, 0, stream>>>(bufH, w_o, x, out, M_, D_, D_);
  // 6. h2 = rmsnorm(x1,norm2)*fg + fb -> bufH
  rmsnorm_film_kernel<<<M_, 256, 0, stream>>>(out, norm2w, fg, fb, bufH);
  // 7. gate = silu(h2 @ w_gate) -> bufQKV (qkv is dead)
  gemm128<1><<<dim3(D3_ / 128, M_ / 128), 256, 0, stream>>>(bufH, w_gate, nullptr, bufQKV, M_, D3_, D_);
  // 8. gu = gate * (h2 @ w_up)  (multiply-into epilogue)
  gemm128<2><<<dim3(D3_ / 128, M_ / 128), 256, 0, stream>>>(bufH, w_up, nullptr, bufQKV, M_, D3_, D_);
  // 9. x2 = x1 + gu @ w_down -> d_out (in-place residual)
  gemm128<3><<<dim3(D_ / 128, M_ / 128), 256, 0, stream>>>(bufQKV, w_down, out, out, M_, D_, D3_);
  // 10. column mean over S
  colmean1<<<dim3(4, B_, 16), 256, 0, stream>>>(out, part);
  colmean2<<<dim3(4, B_), 256, 0, stream>>>(part, cm);
  // 11. state update -> tail of d_out
  state_kernel<<<1, 128, 0, stream>>>(cm, state, w_h2s, w_sg, out + (size_t)M_ * D_);
}

// Round 2
// 2176.432 us; speedup vs baseline: 2.5742x; 2.5742x over previous
//
#include <hip/hip_runtime.h>
#include <hip/hip_bf16.h>

#define EPS_RMS 1.1920929e-07f

constexpr int B_ = 2, S_ = 2048, D_ = 1024, H_ = 16, HD_ = 64, SD_ = 64;
constexpr int M_ = B_ * S_;      // 4096 rows
constexpr int D3_ = 3 * D_;      // 3072

// ---------------- FiLM modulation: state_mod = state @ w_state_mod ----------------
__global__ void film_kernel(const float* __restrict__ state,
                            const float* __restrict__ w_sm,
                            const float* __restrict__ gamma,
                            const float* __restrict__ beta,
                            float* __restrict__ fg, float* __restrict__ fb) {
  int c = blockIdx.x * 256 + threadIdx.x;   // 0..2047
  int b = blockIdx.y;
  float acc = 0.f;
#pragma unroll 8
  for (int k = 0; k < SD_; ++k)
    acc += state[b * SD_ + k] * w_sm[k * (2 * D_) + c];
  if (c < D_) fg[b * D_ + c] = gamma[c] * (1.f + acc);
  else        fb[b * D_ + (c - D_)] = beta[c - D_] + acc;
}

// ---------------- RMSNorm + FiLM: h = rmsnorm(x)*nw*fg + fb ----------------
__global__ __launch_bounds__(256) void rmsnorm_film_kernel(
    const float* __restrict__ X, const float* __restrict__ nw,
    const float* __restrict__ fg, const float* __restrict__ fb,
    float* __restrict__ Hout) {
  int row = blockIdx.x;            // 0..4095
  int b = row / S_;
  int t = threadIdx.x;
  const float4* x4 = (const float4*)(X + (size_t)row * D_);
  float4 xv = x4[t];
  float ss = xv.x * xv.x + xv.y * xv.y + xv.z * xv.z + xv.w * xv.w;
#pragma unroll
  for (int off = 32; off >= 1; off >>= 1) ss += __shfl_xor(ss, off);
  __shared__ float red[4];
  if ((t & 63) == 0) red[t >> 6] = ss;
  __syncthreads();
  float tot = red[0] + red[1] + red[2] + red[3];
  float scale = rsqrtf(tot / (float)D_ + EPS_RMS);
  int d = t * 4;
  const float4 nw4 = *(const float4*)(nw + d);
  const float4 g4  = *(const float4*)(fg + b * D_ + d);
  const float4 b4  = *(const float4*)(fb + b * D_ + d);
  float4 hv;
  hv.x = xv.x * scale * nw4.x * g4.x + b4.x;
  hv.y = xv.y * scale * nw4.y * g4.y + b4.y;
  hv.z = xv.z * scale * nw4.z * g4.z + b4.z;
  hv.w = xv.w * scale * nw4.w * g4.w + b4.w;
  ((float4*)(Hout + (size_t)row * D_))[t] = hv;
}

// ---------------- f32 GEMM: C = A(MxK) @ B(KxN), 128x128x8 tile ----------------
// EPI: 0 = store, 1 = silu(acc), 2 = C *= acc (read-modify), 3 = C = Res + acc
template<int EPI>
__global__ __launch_bounds__(256) void gemm128(
    const float* __restrict__ A, const float* __restrict__ Bw,
    const float* __restrict__ Res, float* __restrict__ C,
    int M, int N, int K) {
  __shared__ float As[8][128];
  __shared__ float Bs[8][128];
  int t = threadIdx.x;
  int bm = blockIdx.y * 128, bn = blockIdx.x * 128;
  int ar = t >> 1, ac = (t & 1) * 4;       // A tile: 128 rows x 8 k
  int br = t >> 5, bc = (t & 31) * 4;      // B tile: 8 k x 128 cols
  int ty = t >> 4, tx = t & 15;            // 8x8 microtile
  float acc[8][8];
#pragma unroll
  for (int i = 0; i < 8; ++i)
#pragma unroll
    for (int j = 0; j < 8; ++j) acc[i][j] = 0.f;

  for (int k0 = 0; k0 < K; k0 += 8) {
    float4 av = *(const float4*)(A + (size_t)(bm + ar) * K + k0 + ac);
    float4 bv = *(const float4*)(Bw + (size_t)(k0 + br) * N + bn + bc);
    As[ac + 0][ar] = av.x; As[ac + 1][ar] = av.y;
    As[ac + 2][ar] = av.z; As[ac + 3][ar] = av.w;
    *(float4*)&Bs[br][bc] = bv;
    __syncthreads();
#pragma unroll
    for (int k = 0; k < 8; ++k) {
      float a[8], bb[8];
      *(float4*)&a[0]  = *(const float4*)&As[k][ty * 8];
      *(float4*)&a[4]  = *(const float4*)&As[k][ty * 8 + 4];
      *(float4*)&bb[0] = *(const float4*)&Bs[k][tx * 8];
      *(float4*)&bb[4] = *(const float4*)&Bs[k][tx * 8 + 4];
#pragma unroll
      for (int i = 0; i < 8; ++i)
#pragma unroll
        for (int j = 0; j < 8; ++j) acc[i][j] += a[i] * bb[j];
    }
    __syncthreads();
  }

#pragma unroll
  for (int i = 0; i < 8; ++i) {
    size_t base = (size_t)(bm + ty * 8 + i) * (size_t)N + bn + tx * 8;
    float vals[8];
#pragma unroll
    for (int j = 0; j < 8; ++j) vals[j] = acc[i][j];
    if constexpr (EPI == 1) {
#pragma unroll
      for (int j = 0; j < 8; ++j) vals[j] = vals[j] / (1.f + __expf(-vals[j]));
    } else if constexpr (EPI == 2) {
      float4 c0 = *(const float4*)(C + base);
      float4 c1 = *(const float4*)(C + base + 4);
      vals[0] *= c0.x; vals[1] *= c0.y; vals[2] *= c0.z; vals[3] *= c0.w;
      vals[4] *= c1.x; vals[5] *= c1.y; vals[6] *= c1.z; vals[7] *= c1.w;
    } else if constexpr (EPI == 3) {
      float4 r0 = *(const float4*)(Res + base);
      float4 r1 = *(const float4*)(Res + base + 4);
      vals[0] += r0.x; vals[1] += r0.y; vals[2] += r0.z; vals[3] += r0.w;
      vals[4] += r1.x; vals[5] += r1.y; vals[6] += r1.z; vals[7] += r1.w;
    }
    float4 o0 = {vals[0], vals[1], vals[2], vals[3]};
    float4 o1 = {vals[4], vals[5], vals[6], vals[7]};
    *(float4*)(C + base) = o0;
    *(float4*)(C + base + 4) = o1;
  }
}

// ---------------- tiled causal flash attention ----------------
// Block = 256 threads: 128 query rows x 2 k-halves. Q,O in registers (1 row/thread,
// no cross-lane in main loop). K/V 64x64 f32 tiles staged coalesced in LDS; all
// inner-loop LDS reads are wave-uniform broadcasts (conflict-free).
__global__ __launch_bounds__(256, 2) void attn_tiled_kernel(
    const float* __restrict__ qkv, float* __restrict__ AO) {
  __shared__ float lds[8192 + 256];
  float* Ks = lds;          // 64x64
  float* Vs = lds + 4096;   // 64x64
  float* SO = lds;          // reused after main loop: 128x64 output staging
  float* ml = lds + 8192;   // 128 x (m,l) from half1

  int t = threadIdx.x;
  int x = blockIdx.x;
  // work-balanced mapping: first 256 blocks take q-tiles 0..7, second 256 take 15..8
  int second = x >> 8;
  int pair = x & 255;
  int h = pair & 15;
  int bb = (pair >> 4) & 1;
  int qt3 = (pair >> 5) & 7;
  int qt = second ? (15 - qt3) : qt3;
  int q0 = qt * 128;
  int r = t & 127, half = t >> 7;
  int q = q0 + r;

  const float* qptr = qkv + ((size_t)(bb * S_ + q) * 3) * D_ + h * HD_;
  float4 qv[16];
#pragma unroll
  for (int i = 0; i < 16; ++i) qv[i] = ((const float4*)qptr)[i];
  float4 O4[16];
#pragma unroll
  for (int i = 0; i < 16; ++i) O4[i] = make_float4(0.f, 0.f, 0.f, 0.f);
  float m = -INFINITY, l = 0.f;

  for (int kt = 0; kt < q0 + 128; kt += 64) {
    // stage K,V tiles (coalesced: 16 lanes cover one 256B row)
#pragma unroll
    for (int p = 0; p < 4; ++p) {
      int f = t + 256 * p;            // 0..1023
      int row = f >> 4, c4 = (f & 15) * 4;
      const float* src = qkv + ((size_t)(bb * S_ + kt + row) * 3 + 1) * D_ + h * HD_ + c4;
      *(float4*)&Ks[row * 64 + c4] = *(const float4*)src;
      *(float4*)&Vs[row * 64 + c4] = *(const float4*)(src + D_);   // V field
    }
    __syncthreads();
    int k0 = kt + half * 32;
    if (k0 <= q) {
      const float* Kb = Ks + half * 32 * 64;
      const float* Vb = Vs + half * 32 * 64;
      float p_[32];
#pragma unroll
      for (int jj = 0; jj < 32; jj += 4) {     // 4 independent acc chains
        float s0 = 0.f, s1 = 0.f, s2 = 0.f, s3 = 0.f;
#pragma unroll
        for (int d4 = 0; d4 < 16; ++d4) {
          float4 k0v = *(const float4*)(Kb + (jj + 0) * 64 + d4 * 4);
          float4 k1v = *(const float4*)(Kb + (jj + 1) * 64 + d4 * 4);
          float4 k2v = *(const float4*)(Kb + (jj + 2) * 64 + d4 * 4);
          float4 k3v = *(const float4*)(Kb + (jj + 3) * 64 + d4 * 4);
          float4 qq = qv[d4];
          s0 += qq.x * k0v.x + qq.y * k0v.y + qq.z * k0v.z + qq.w * k0v.w;
          s1 += qq.x * k1v.x + qq.y * k1v.y + qq.z * k1v.z + qq.w * k1v.w;
          s2 += qq.x * k2v.x + qq.y * k2v.y + qq.z * k2v.z + qq.w * k2v.w;
          s3 += qq.x * k3v.x + qq.y * k3v.y + qq.z * k3v.z + qq.w * k3v.w;
        }
        p_[jj + 0] = s0; p_[jj + 1] = s1; p_[jj + 2] = s2; p_[jj + 3] = s3;
      }
      float mt = -INFINITY;
#pragma unroll
      for (int j = 0; j < 32; ++j) {
        p_[j] = (k0 + j <= q) ? p_[j] * 0.125f : -INFINITY;   // causal mask
        mt = fmaxf(mt, p_[j]);
      }
      float mnew = fmaxf(m, mt);
      float corr = __expf(m - mnew);    // m=-inf first iter -> 0
      float psum = 0.f;
#pragma unroll
      for (int j = 0; j < 32; ++j) { p_[j] = __expf(p_[j] - mnew); psum += p_[j]; }
      l = l * corr + psum;
      m = mnew;
#pragma unroll
      for (int d4 = 0; d4 < 16; ++d4) {
        float4 o = O4[d4];
        o.x *= corr; o.y *= corr; o.z *= corr; o.w *= corr;
#pragma unroll
        for (int j = 0; j < 32; ++j) {
          float4 v = *(const float4*)(Vb + j * 64 + d4 * 4);
          o.x += p_[j] * v.x; o.y += p_[j] * v.y;
          o.z += p_[j] * v.z; o.w += p_[j] * v.w;
        }
        O4[d4] = o;
      }
    }
    __syncthreads();
  }

  // merge the two k-halves of each row via LDS (half0 always has valid m,l)
  if (half) {
#pragma unroll
    for (int d4 = 0; d4 < 16; ++d4) *(float4*)&SO[r * 64 + d4 * 4] = O4[d4];
    ml[r * 2] = m; ml[r * 2 + 1] = l;
  }
  __syncthreads();
  if (!half) {
    float m1 = ml[r * 2], l1 = ml[r * 2 + 1];
    float mn = fmaxf(m, m1);
    float c0 = __expf(m - mn), c1 = __expf(m1 - mn);   // m1=-inf -> c1=0
    float linv = 1.f / (l * c0 + l1 * c1);
#pragma unroll
    for (int d4 = 0; d4 < 16; ++d4) {
      float4 o1 = *(const float4*)&SO[r * 64 + d4 * 4];
      float4 o0 = O4[d4];
      float4 res;
      res.x = (o0.x * c0 + o1.x * c1) * linv;
      res.y = (o0.y * c0 + o1.y * c1) * linv;
      res.z = (o0.z * c0 + o1.z * c1) * linv;
      res.w = (o0.w * c0 + o1.w * c1) * linv;
      *(float4*)&SO[r * 64 + d4 * 4] = res;
    }
  }
  __syncthreads();
  // cooperative coalesced store: 128 rows x 64 cols
#pragma unroll
  for (int p = 0; p < 8; ++p) {
    int f = t + 256 * p;            // 0..2047
    int row = f >> 4, c4 = (f & 15) * 4;
    *(float4*)(AO + (size_t)(bb * S_ + q0 + row) * D_ + h * HD_ + c4) =
        *(const float4*)&SO[f * 4];
  }
}

// ---------------- column mean over S (two stage) ----------------
__global__ void colmean1(const float* __restrict__ X, float* __restrict__ part) {
  int d = blockIdx.x * 256 + threadIdx.x;  // 0..1023
  int b = blockIdx.y;
  int ch = blockIdx.z;                     // 0..15
  float s = 0.f;
  int s0 = ch * (S_ / 16);
  for (int i = 0; i < S_ / 16; ++i)
    s += X[(size_t)(b * S_ + s0 + i) * D_ + d];
  part[(b * 16 + ch) * D_ + d] = s;
}
__global__ void colmean2(const float* __restrict__ part, float* __restrict__ cm) {
  int d = blockIdx.x * 256 + threadIdx.x;
  int b = blockIdx.y;
  float s = 0.f;
#pragma unroll
  for (int c = 0; c < 16; ++c) s += part[(b * 16 + c) * D_ + d];
  cm[b * D_ + d] = s * (1.f / (float)S_);
}

// ---------------- recurrent state update ----------------
__global__ __launch_bounds__(128) void state_kernel(
    const float* __restrict__ cm, const float* __restrict__ state,
    const float* __restrict__ w_h2s, const float* __restrict__ w_sg,
    float* __restrict__ out_tail) {
  int t = threadIdx.x;        // 0..127
  int b = t >> 6, j = t & 63;
  float ni = 0.f;
  for (int k = 0; k < D_; ++k) ni += cm[b * D_ + k] * w_h2s[k * SD_ + j];
  __shared__ float ni_s[128];
  ni_s[t] = ni;
  __syncthreads();
  float g = 0.f;
#pragma unroll
  for (int k = 0; k < SD_; ++k) g += state[b * SD_ + k] * w_sg[k * SD_ + j];
#pragma unroll
  for (int k = 0; k < SD_; ++k) g += ni_s[b * SD_ + k] * w_sg[(SD_ + k) * SD_ + j];
  g = 1.f / (1.f + __expf(-g));
  float st = state[b * SD_ + j];
  out_tail[b * SD_ + j] = st * (1.f - g) + ni * g;
}

extern "C" void kernel_launch(void* const* d_in, const int* in_sizes, int n_in,
                              void* d_out, int out_size, void* d_ws, size_t ws_size,
                              hipStream_t stream) {
  const float* x      = (const float*)d_in[0];
  const float* gamma  = (const float*)d_in[1];
  const float* beta   = (const float*)d_in[2];
  const float* state  = (const float*)d_in[3];
  const float* w_qkv  = (const float*)d_in[4];
  const float* w_o    = (const float*)d_in[5];
  const float* w_gate = (const float*)d_in[6];
  const float* w_up   = (const float*)d_in[7];
  const float* w_down = (const float*)d_in[8];
  const float* norm1w = (const float*)d_in[9];
  const float* norm2w = (const float*)d_in[10];
  const float* w_sm   = (const float*)d_in[11];
  const float* w_h2s  = (const float*)d_in[12];
  const float* w_sg   = (const float*)d_in[13];
  float* out = (float*)d_out;

  float* ws   = (float*)d_ws;
  float* fg   = ws;                  // 2048
  float* fb   = ws + 2048;           // 2048
  float* cm   = ws + 4096;           // 2048
  float* part = ws + 8192;           // 32768
  float* bufH   = ws + 65536;                      // 4M floats (h / attn_out / h2)
  float* bufQKV = ws + 65536 + (size_t)M_ * D_;    // 12M floats (qkv / gate*up)

  // 1. FiLM params
  film_kernel<<<dim3(8, B_), 256, 0, stream>>>(state, w_sm, gamma, beta, fg, fb);
  // 2. h = rmsnorm(x,norm1)*fg + fb
  rmsnorm_film_kernel<<<M_, 256, 0, stream>>>(x, norm1w, fg, fb, bufH);
  // 3. qkv = h @ w_qkv
  gemm128<0><<<dim3(D3_ / 128, M_ / 128), 256, 0, stream>>>(bufH, w_qkv, nullptr, bufQKV, M_, D3_, D_);
  // 4. attention -> bufH (h is dead)
  attn_tiled_kernel<<<512, 256, 0, stream>>>(bufQKV, bufH);
  // 5. x1 = x + AO @ w_o -> d_out
  gemm128<3><<<dim3(D_ / 128, M_ / 128), 256, 0, stream>>>(bufH, w_o, x, out, M_, D_, D_);
  // 6. h2 = rmsnorm(x1,norm2)*fg + fb -> bufH
  rmsnorm_film_kernel<<<M_, 256, 0, stream>>>(out, norm2w, fg, fb, bufH);
  // 7. gate = silu(h2 @ w_gate) -> bufQKV (qkv is dead)
  gemm128<1><<<dim3(D3_ / 128, M_ / 128), 256, 0, stream>>>(bufH, w_gate, nullptr, bufQKV, M_, D3_, D_);
  // 8. gu = gate * (h2 @ w_up)  (multiply-into epilogue)
  gemm128<2><<<dim3(D3_ / 128, M_ / 128), 256, 0, stream>>>(bufH, w_up, nullptr, bufQKV, M_, D3_, D_);
  // 9. x2 = x1 + gu @ w_down -> d_out (in-place residual)
  gemm128<3><<<dim3(D_ / 128, M_ / 128), 256, 0, stream>>>(bufQKV, w_down, out, out, M_, D_, D3_);
  // 10. column mean over S
  colmean1<<<dim3(4, B_, 16), 256, 0, stream>>>(out, part);
  colmean2<<<dim3(4, B_), 256, 0, stream>>>(part, cm);
  // 11. state update -> tail of d_out
  state_kernel<<<1, 128, 0, stream>>>(cm, state, w_h2s, w_sg, out + (size_t)M_ * D_);
}

// Round 3
// 1264.654 us; speedup vs baseline: 4.4301x; 1.7210x over previous
//
#include <hip/hip_runtime.h>
#include <hip/hip_bf16.h>

#define EPS_RMS 1.1920929e-07f

constexpr int B_ = 2, S_ = 2048, D_ = 1024, H_ = 16, HD_ = 64, SD_ = 64;
constexpr int M_ = B_ * S_;      // 4096 rows
constexpr int D3_ = 3 * D_;      // 3072

using short8 = __attribute__((ext_vector_type(8))) short;
using f32x4  = __attribute__((ext_vector_type(4))) float;

static __device__ __forceinline__ ushort f2bf(float x) {
  __hip_bfloat16 h = __float2bfloat16(x);
  return *reinterpret_cast<ushort*>(&h);
}
static __device__ __forceinline__ float bf2f(ushort u) {
  __hip_bfloat16 h;
  *reinterpret_cast<ushort*>(&h) = u;
  return __bfloat162float(h);
}
struct alignas(8) bf4 { ushort a, b, c, d; };

// ---------------- FiLM modulation ----------------
__global__ void film_kernel(const float* __restrict__ state,
                            const float* __restrict__ w_sm,
                            const float* __restrict__ gamma,
                            const float* __restrict__ beta,
                            float* __restrict__ fg, float* __restrict__ fb) {
  int c = blockIdx.x * 256 + threadIdx.x;   // 0..2047
  int b = blockIdx.y;
  float acc = 0.f;
#pragma unroll 8
  for (int k = 0; k < SD_; ++k)
    acc += state[b * SD_ + k] * w_sm[k * (2 * D_) + c];
  if (c < D_) fg[b * D_ + c] = gamma[c] * (1.f + acc);
  else        fb[b * D_ + (c - D_)] = beta[c - D_] + acc;
}

// ---------------- RMSNorm + FiLM -> bf16 ----------------
__global__ __launch_bounds__(256) void rmsnorm_film_kernel(
    const float* __restrict__ X, const float* __restrict__ nw,
    const float* __restrict__ fg, const float* __restrict__ fb,
    ushort* __restrict__ Hout) {
  int row = blockIdx.x;            // 0..4095
  int b = row / S_;
  int t = threadIdx.x;
  const float4* x4 = (const float4*)(X + (size_t)row * D_);
  float4 xv = x4[t];
  float ss = xv.x * xv.x + xv.y * xv.y + xv.z * xv.z + xv.w * xv.w;
#pragma unroll
  for (int off = 32; off >= 1; off >>= 1) ss += __shfl_xor(ss, off);
  __shared__ float red[4];
  if ((t & 63) == 0) red[t >> 6] = ss;
  __syncthreads();
  float tot = red[0] + red[1] + red[2] + red[3];
  float scale = rsqrtf(tot / (float)D_ + EPS_RMS);
  int d = t * 4;
  const float4 nw4 = *(const float4*)(nw + d);
  const float4 g4  = *(const float4*)(fg + b * D_ + d);
  const float4 b4  = *(const float4*)(fb + b * D_ + d);
  bf4 hv;
  hv.a = f2bf(xv.x * scale * nw4.x * g4.x + b4.x);
  hv.b = f2bf(xv.y * scale * nw4.y * g4.y + b4.y);
  hv.c = f2bf(xv.z * scale * nw4.z * g4.z + b4.z);
  hv.d = f2bf(xv.w * scale * nw4.w * g4.w + b4.w);
  *(bf4*)(Hout + (size_t)row * D_ + d) = hv;
}

// ---------------- weight transpose + f32->bf16: Wt[n][k] = bf16(W[k][n]) ----------------
__global__ __launch_bounds__(256) void transpose_bf16(
    const float* __restrict__ W, ushort* __restrict__ Wt, int K, int N) {
  __shared__ float tile[32][33];
  int n0 = blockIdx.x * 32, k0 = blockIdx.y * 32;
  int t = threadIdx.x;
  int c = t & 31, r = t >> 5;      // 8 rows per pass
#pragma unroll
  for (int p = 0; p < 4; ++p)
    tile[r + 8 * p][c] = W[(size_t)(k0 + r + 8 * p) * N + n0 + c];
  __syncthreads();
#pragma unroll
  for (int p = 0; p < 4; ++p)
    Wt[(size_t)(n0 + r + 8 * p) * K + k0 + c] = f2bf(tile[c][r + 8 * p]);
}

// ---------------- bf16 MFMA GEMM: C = A(MxK) @ Bt(NxK)^T ----------------
// 128x128 tile, BK=64, 4 waves each 64x64. XOR-swizzled LDS (T2).
// EPI: 0 = f32 store; 1 = silu->bf16; 2 = gate*acc->bf16; 3 = Res+acc->f32
template<int EPI>
__global__ __launch_bounds__(256, 2) void gemm_mfma(
    const ushort* __restrict__ A, const ushort* __restrict__ Bt,
    const float* __restrict__ Res, const ushort* __restrict__ Gate,
    float* __restrict__ Cf, ushort* __restrict__ Cb,
    int M, int N, int K) {
  __shared__ ushort As[128 * 64];
  __shared__ ushort Bs[128 * 64];
  char* Au = (char*)As;
  char* Bu = (char*)Bs;
  int t = threadIdx.x;
  int bm = blockIdx.y * 128, bn = blockIdx.x * 128;
  int lane = t & 63, wid = t >> 6;
  int wr = wid >> 1, wc = wid & 1;
  int l15 = lane & 15, l4 = lane >> 4;
  int swz = l15 & 7;                       // XOR applied to k-slot on reads

  // staging geometry: 4 passes x 256 threads x 16B cover one 128x64 bf16 tile
  int ldsoff[4];
  const ushort* pA[4];
  const ushort* pB[4];
#pragma unroll
  for (int p = 0; p < 4; ++p) {
    int flat = p * 256 + t;                // 0..1023
    int row = flat >> 3, slot = flat & 7;
    ldsoff[p] = row * 128 + ((slot ^ (row & 7)) << 4);
    pA[p] = A + (size_t)(bm + row) * K + slot * 8;
    pB[p] = Bt + (size_t)(bn + row) * K + slot * 8;
  }

  f32x4 acc[4][4];
#pragma unroll
  for (int m = 0; m < 4; ++m)
#pragma unroll
    for (int n = 0; n < 4; ++n) acc[m][n] = (f32x4){0.f, 0.f, 0.f, 0.f};

  uint4 ra[4], rb[4];
#pragma unroll
  for (int p = 0; p < 4; ++p) { ra[p] = *(const uint4*)pA[p]; rb[p] = *(const uint4*)pB[p]; }

  int nk = K >> 6;
  for (int kt = 0; kt < nk; ++kt) {
    __syncthreads();                       // previous tile's reads done
#pragma unroll
    for (int p = 0; p < 4; ++p) {
      *(uint4*)(Au + ldsoff[p]) = ra[p];
      *(uint4*)(Bu + ldsoff[p]) = rb[p];
    }
    __syncthreads();
    if (kt + 1 < nk) {
#pragma unroll
      for (int p = 0; p < 4; ++p) {
        pA[p] += 64; pB[p] += 64;
        ra[p] = *(const uint4*)pA[p];
        rb[p] = *(const uint4*)pB[p];
      }
    }
#pragma unroll
    for (int kk = 0; kk < 2; ++kk) {
      int tslot = ((kk * 4 + l4) ^ swz) << 4;   // swizzled 16B slot within row
      short8 a[4], b[4];
#pragma unroll
      for (int i = 0; i < 4; ++i) {
        int arow = wr * 64 + i * 16 + l15;
        int brow = wc * 64 + i * 16 + l15;
        a[i] = *(const short8*)(Au + arow * 128 + tslot);
        b[i] = *(const short8*)(Bu + brow * 128 + tslot);
      }
#pragma unroll
      for (int m = 0; m < 4; ++m)
#pragma unroll
        for (int n = 0; n < 4; ++n)
          acc[m][n] = __builtin_amdgcn_mfma_f32_16x16x32_bf16(a[m], b[n], acc[m][n], 0, 0, 0);
    }
  }

  // epilogue: D col = lane&15, row = (lane>>4)*4 + j   [m89 verified]
#pragma unroll
  for (int m = 0; m < 4; ++m) {
#pragma unroll
    for (int n = 0; n < 4; ++n) {
      int row0 = bm + wr * 64 + m * 16 + l4 * 4;
      int col  = bn + wc * 64 + n * 16 + l15;
#pragma unroll
      for (int j = 0; j < 4; ++j) {
        float v = acc[m][n][j];
        size_t idx = (size_t)(row0 + j) * (size_t)N + col;
        if constexpr (EPI == 0) {
          Cf[idx] = v;
        } else if constexpr (EPI == 1) {
          Cb[idx] = f2bf(v / (1.f + __expf(-v)));
        } else if constexpr (EPI == 2) {
          Cb[idx] = f2bf(bf2f(Gate[idx]) * v);
        } else {
          Cf[idx] = Res[idx] + v;
        }
      }
    }
  }
}

// ---------------- tiled causal flash attention (f32 compute, bf16 out) ----------------
__global__ __launch_bounds__(256, 2) void attn_tiled_kernel(
    const float* __restrict__ qkv, ushort* __restrict__ AObf) {
  __shared__ float lds[8192 + 256];
  float* Ks = lds;          // 64x64
  float* Vs = lds + 4096;   // 64x64
  float* SO = lds;          // reused after main loop: 128x64 output staging
  float* ml = lds + 8192;   // 128 x (m,l) from half1

  int t = threadIdx.x;
  int x = blockIdx.x;
  int second = x >> 8;
  int pair = x & 255;
  int h = pair & 15;
  int bb = (pair >> 4) & 1;
  int qt3 = (pair >> 5) & 7;
  int qt = second ? (15 - qt3) : qt3;
  int q0 = qt * 128;
  int r = t & 127, half = t >> 7;
  int q = q0 + r;

  const float* qptr = qkv + ((size_t)(bb * S_ + q) * 3) * D_ + h * HD_;
  float4 qv[16];
#pragma unroll
  for (int i = 0; i < 16; ++i) qv[i] = ((const float4*)qptr)[i];
  float4 O4[16];
#pragma unroll
  for (int i = 0; i < 16; ++i) O4[i] = make_float4(0.f, 0.f, 0.f, 0.f);
  float m = -INFINITY, l = 0.f;

  for (int kt = 0; kt < q0 + 128; kt += 64) {
#pragma unroll
    for (int p = 0; p < 4; ++p) {
      int f = t + 256 * p;            // 0..1023
      int row = f >> 4, c4 = (f & 15) * 4;
      const float* src = qkv + ((size_t)(bb * S_ + kt + row) * 3 + 1) * D_ + h * HD_ + c4;
      *(float4*)&Ks[row * 64 + c4] = *(const float4*)src;
      *(float4*)&Vs[row * 64 + c4] = *(const float4*)(src + D_);
    }
    __syncthreads();
    int k0 = kt + half * 32;
    if (k0 <= q) {
      const float* Kb = Ks + half * 32 * 64;
      const float* Vb = Vs + half * 32 * 64;
      float p_[32];
#pragma unroll
      for (int jj = 0; jj < 32; jj += 4) {
        float s0 = 0.f, s1 = 0.f, s2 = 0.f, s3 = 0.f;
#pragma unroll
        for (int d4 = 0; d4 < 16; ++d4) {
          float4 k0v = *(const float4*)(Kb + (jj + 0) * 64 + d4 * 4);
          float4 k1v = *(const float4*)(Kb + (jj + 1) * 64 + d4 * 4);
          float4 k2v = *(const float4*)(Kb + (jj + 2) * 64 + d4 * 4);
          float4 k3v = *(const float4*)(Kb + (jj + 3) * 64 + d4 * 4);
          float4 qq = qv[d4];
          s0 += qq.x * k0v.x + qq.y * k0v.y + qq.z * k0v.z + qq.w * k0v.w;
          s1 += qq.x * k1v.x + qq.y * k1v.y + qq.z * k1v.z + qq.w * k1v.w;
          s2 += qq.x * k2v.x + qq.y * k2v.y + qq.z * k2v.z + qq.w * k2v.w;
          s3 += qq.x * k3v.x + qq.y * k3v.y + qq.z * k3v.z + qq.w * k3v.w;
        }
        p_[jj + 0] = s0; p_[jj + 1] = s1; p_[jj + 2] = s2; p_[jj + 3] = s3;
      }
      float mt = -INFINITY;
#pragma unroll
      for (int j = 0; j < 32; ++j) {
        p_[j] = (k0 + j <= q) ? p_[j] * 0.125f : -INFINITY;
        mt = fmaxf(mt, p_[j]);
      }
      float mnew = fmaxf(m, mt);
      float corr = __expf(m - mnew);
      float psum = 0.f;
#pragma unroll
      for (int j = 0; j < 32; ++j) { p_[j] = __expf(p_[j] - mnew); psum += p_[j]; }
      l = l * corr + psum;
      m = mnew;
#pragma unroll
      for (int d4 = 0; d4 < 16; ++d4) {
        float4 o = O4[d4];
        o.x *= corr; o.y *= corr; o.z *= corr; o.w *= corr;
#pragma unroll
        for (int j = 0; j < 32; ++j) {
          float4 v = *(const float4*)(Vb + j * 64 + d4 * 4);
          o.x += p_[j] * v.x; o.y += p_[j] * v.y;
          o.z += p_[j] * v.z; o.w += p_[j] * v.w;
        }
        O4[d4] = o;
      }
    }
    __syncthreads();
  }

  if (half) {
#pragma unroll
    for (int d4 = 0; d4 < 16; ++d4) *(float4*)&SO[r * 64 + d4 * 4] = O4[d4];
    ml[r * 2] = m; ml[r * 2 + 1] = l;
  }
  __syncthreads();
  if (!half) {
    float m1 = ml[r * 2], l1 = ml[r * 2 + 1];
    float mn = fmaxf(m, m1);
    float c0 = __expf(m - mn), c1 = __expf(m1 - mn);
    float linv = 1.f / (l * c0 + l1 * c1);
#pragma unroll
    for (int d4 = 0; d4 < 16; ++d4) {
      float4 o1 = *(const float4*)&SO[r * 64 + d4 * 4];
      float4 o0 = O4[d4];
      float4 res;
      res.x = (o0.x * c0 + o1.x * c1) * linv;
      res.y = (o0.y * c0 + o1.y * c1) * linv;
      res.z = (o0.z * c0 + o1.z * c1) * linv;
      res.w = (o0.w * c0 + o1.w * c1) * linv;
      *(float4*)&SO[r * 64 + d4 * 4] = res;
    }
  }
  __syncthreads();
#pragma unroll
  for (int p = 0; p < 8; ++p) {
    int f = t + 256 * p;            // 0..2047
    int row = f >> 4, c4 = (f & 15) * 4;
    float4 v = *(const float4*)&SO[f * 4];
    bf4 pk;
    pk.a = f2bf(v.x); pk.b = f2bf(v.y); pk.c = f2bf(v.z); pk.d = f2bf(v.w);
    *(bf4*)(AObf + (size_t)(bb * S_ + q0 + row) * D_ + h * HD_ + c4) = pk;
  }
}

// ---------------- column mean over S (two stage) ----------------
__global__ void colmean1(const float* __restrict__ X, float* __restrict__ part) {
  int d = blockIdx.x * 256 + threadIdx.x;  // 0..1023
  int b = blockIdx.y;
  int ch = blockIdx.z;                     // 0..15
  float s = 0.f;
  int s0 = ch * (S_ / 16);
  for (int i = 0; i < S_ / 16; ++i)
    s += X[(size_t)(b * S_ + s0 + i) * D_ + d];
  part[(b * 16 + ch) * D_ + d] = s;
}
__global__ void colmean2(const float* __restrict__ part, float* __restrict__ cm) {
  int d = blockIdx.x * 256 + threadIdx.x;
  int b = blockIdx.y;
  float s = 0.f;
#pragma unroll
  for (int c = 0; c < 16; ++c) s += part[(b * 16 + c) * D_ + d];
  cm[b * D_ + d] = s * (1.f / (float)S_);
}

// ---------------- recurrent state update ----------------
__global__ __launch_bounds__(128) void state_kernel(
    const float* __restrict__ cm, const float* __restrict__ state,
    const float* __restrict__ w_h2s, const float* __restrict__ w_sg,
    float* __restrict__ out_tail) {
  int t = threadIdx.x;        // 0..127
  int b = t >> 6, j = t & 63;
  float ni = 0.f;
  for (int k = 0; k < D_; ++k) ni += cm[b * D_ + k] * w_h2s[k * SD_ + j];
  __shared__ float ni_s[128];
  ni_s[t] = ni;
  __syncthreads();
  float g = 0.f;
#pragma unroll
  for (int k = 0; k < SD_; ++k) g += state[b * SD_ + k] * w_sg[k * SD_ + j];
#pragma unroll
  for (int k = 0; k < SD_; ++k) g += ni_s[b * SD_ + k] * w_sg[(SD_ + k) * SD_ + j];
  g = 1.f / (1.f + __expf(-g));
  float st = state[b * SD_ + j];
  out_tail[b * SD_ + j] = st * (1.f - g) + ni * g;
}

extern "C" void kernel_launch(void* const* d_in, const int* in_sizes, int n_in,
                              void* d_out, int out_size, void* d_ws, size_t ws_size,
                              hipStream_t stream) {
  const float* x      = (const float*)d_in[0];
  const float* gamma  = (const float*)d_in[1];
  const float* beta   = (const float*)d_in[2];
  const float* state  = (const float*)d_in[3];
  const float* w_qkv  = (const float*)d_in[4];
  const float* w_o    = (const float*)d_in[5];
  const float* w_gate = (const float*)d_in[6];
  const float* w_up   = (const float*)d_in[7];
  const float* w_down = (const float*)d_in[8];
  const float* norm1w = (const float*)d_in[9];
  const float* norm2w = (const float*)d_in[10];
  const float* w_sm   = (const float*)d_in[11];
  const float* w_h2s  = (const float*)d_in[12];
  const float* w_sg   = (const float*)d_in[13];
  float* out = (float*)d_out;

  float* ws = (float*)d_ws;
  // workspace map (float units)
  float*  fg     = ws;                        // 2048
  float*  fb     = ws + 2048;                 // 2048
  float*  cm     = ws + 4096;                 // 2048
  float*  part   = ws + 8192;                 // 32768
  ushort* h_bf   = (ushort*)(ws + 65536);     // M*D bf16   (2M floats)
  ushort* AO_bf  = (ushort*)(ws + 65536 + 2097152);          // M*D bf16 (2M floats)
  ushort* wT     = (ushort*)(ws + 65536 + 2 * 2097152);      // up to 3072x1024 bf16 (1.573M floats)
  float*  qkv    = ws + 65536 + 2 * 2097152 + 1572864;       // M*3D f32 (12.58M floats)
  ushort* gatebf = (ushort*)qkv;                             // reuses qkv slot (qkv dead)
  ushort* gu_bf  = (ushort*)(qkv + 6291456);                 // second half of qkv slot

  // 1. FiLM params
  film_kernel<<<dim3(8, B_), 256, 0, stream>>>(state, w_sm, gamma, beta, fg, fb);
  // 2. h = rmsnorm(x,norm1)*fg + fb  -> bf16
  rmsnorm_film_kernel<<<M_, 256, 0, stream>>>(x, norm1w, fg, fb, h_bf);
  // 3. qkv = h @ w_qkv   (f32 out for attention)
  transpose_bf16<<<dim3(D3_ / 32, D_ / 32), 256, 0, stream>>>(w_qkv, wT, D_, D3_);
  gemm_mfma<0><<<dim3(D3_ / 128, M_ / 128), 256, 0, stream>>>(
      h_bf, wT, nullptr, nullptr, qkv, nullptr, M_, D3_, D_);
  // 4. attention -> AO bf16
  attn_tiled_kernel<<<512, 256, 0, stream>>>(qkv, AO_bf);
  // 5. x1 = x + AO @ w_o -> d_out
  transpose_bf16<<<dim3(D_ / 32, D_ / 32), 256, 0, stream>>>(w_o, wT, D_, D_);
  gemm_mfma<3><<<dim3(D_ / 128, M_ / 128), 256, 0, stream>>>(
      AO_bf, wT, x, nullptr, out, nullptr, M_, D_, D_);
  // 6. h2 = rmsnorm(x1,norm2)*fg + fb -> bf16
  rmsnorm_film_kernel<<<M_, 256, 0, stream>>>(out, norm2w, fg, fb, h_bf);
  // 7. gate = silu(h2 @ w_gate) -> bf16 (qkv slot, qkv dead)
  transpose_bf16<<<dim3(D3_ / 32, D_ / 32), 256, 0, stream>>>(w_gate, wT, D_, D3_);
  gemm_mfma<1><<<dim3(D3_ / 128, M_ / 128), 256, 0, stream>>>(
      h_bf, wT, nullptr, nullptr, nullptr, gatebf, M_, D3_, D_);
  // 8. gu = gate * (h2 @ w_up) -> bf16
  transpose_bf16<<<dim3(D3_ / 32, D_ / 32), 256, 0, stream>>>(w_up, wT, D_, D3_);
  gemm_mfma<2><<<dim3(D3_ / 128, M_ / 128), 256, 0, stream>>>(
      h_bf, wT, nullptr, gatebf, nullptr, gu_bf, M_, D3_, D_);
  // 9. x2 = x1 + gu @ w_down -> d_out (in-place residual)
  transpose_bf16<<<dim3(D_ / 32, D3_ / 32), 256, 0, stream>>>(w_down, wT, D3_, D_);
  gemm_mfma<3><<<dim3(D_ / 128, M_ / 128), 256, 0, stream>>>(
      gu_bf, wT, out, nullptr, out, nullptr, M_, D_, D3_);
  // 10. column mean over S
  colmean1<<<dim3(4, B_, 16), 256, 0, stream>>>(out, part);
  colmean2<<<dim3(4, B_), 256, 0, stream>>>(part, cm);
  // 11. state update -> tail of d_out
  state_kernel<<<1, 128, 0, stream>>>(cm, state, w_h2s, w_sg, out + (size_t)M_ * D_);
}

// Round 4
// 779.037 us; speedup vs baseline: 7.1915x; 1.6234x over previous
//
#include <hip/hip_runtime.h>
#include <hip/hip_bf16.h>

#define EPS_RMS 1.1920929e-07f

constexpr int B_ = 2, S_ = 2048, D_ = 1024, H_ = 16, HD_ = 64, SD_ = 64;
constexpr int M_ = B_ * S_;      // 4096 rows
constexpr int D3_ = 3 * D_;      // 3072

using short8 = __attribute__((ext_vector_type(8))) short;
using f32x4  = __attribute__((ext_vector_type(4))) float;
using f32x16 = __attribute__((ext_vector_type(16))) float;

static __device__ __forceinline__ ushort f2bf(float x) {
  __hip_bfloat16 h = __float2bfloat16(x);
  return *reinterpret_cast<ushort*>(&h);
}
static __device__ __forceinline__ float bf2f(ushort u) {
  __hip_bfloat16 h;
  *reinterpret_cast<ushort*>(&h) = u;
  return __bfloat162float(h);
}
static __device__ __forceinline__ unsigned pk2(float lo, float hi) {
  return (unsigned)f2bf(lo) | ((unsigned)f2bf(hi) << 16);
}
struct alignas(8) bf4 { ushort a, b, c, d; };

// ---------------- FiLM modulation ----------------
__global__ void film_kernel(const float* __restrict__ state,
                            const float* __restrict__ w_sm,
                            const float* __restrict__ gamma,
                            const float* __restrict__ beta,
                            float* __restrict__ fg, float* __restrict__ fb) {
  int c = blockIdx.x * 256 + threadIdx.x;   // 0..2047
  int b = blockIdx.y;
  float acc = 0.f;
#pragma unroll 8
  for (int k = 0; k < SD_; ++k)
    acc += state[b * SD_ + k] * w_sm[k * (2 * D_) + c];
  if (c < D_) fg[b * D_ + c] = gamma[c] * (1.f + acc);
  else        fb[b * D_ + (c - D_)] = beta[c - D_] + acc;
}

// ---------------- RMSNorm + FiLM -> bf16 ----------------
__global__ __launch_bounds__(256) void rmsnorm_film_kernel(
    const float* __restrict__ X, const float* __restrict__ nw,
    const float* __restrict__ fg, const float* __restrict__ fb,
    ushort* __restrict__ Hout) {
  int row = blockIdx.x;            // 0..4095
  int b = row / S_;
  int t = threadIdx.x;
  const float4* x4 = (const float4*)(X + (size_t)row * D_);
  float4 xv = x4[t];
  float ss = xv.x * xv.x + xv.y * xv.y + xv.z * xv.z + xv.w * xv.w;
#pragma unroll
  for (int off = 32; off >= 1; off >>= 1) ss += __shfl_xor(ss, off);
  __shared__ float red[4];
  if ((t & 63) == 0) red[t >> 6] = ss;
  __syncthreads();
  float tot = red[0] + red[1] + red[2] + red[3];
  float scale = rsqrtf(tot / (float)D_ + EPS_RMS);
  int d = t * 4;
  const float4 nw4 = *(const float4*)(nw + d);
  const float4 g4  = *(const float4*)(fg + b * D_ + d);
  const float4 b4  = *(const float4*)(fb + b * D_ + d);
  bf4 hv;
  hv.a = f2bf(xv.x * scale * nw4.x * g4.x + b4.x);
  hv.b = f2bf(xv.y * scale * nw4.y * g4.y + b4.y);
  hv.c = f2bf(xv.z * scale * nw4.z * g4.z + b4.z);
  hv.d = f2bf(xv.w * scale * nw4.w * g4.w + b4.w);
  *(bf4*)(Hout + (size_t)row * D_ + d) = hv;
}

// ---------------- weight transpose + f32->bf16: Wt[n][k] = bf16(W[k][n]) ----------------
__global__ __launch_bounds__(256) void transpose_bf16(
    const float* __restrict__ W, ushort* __restrict__ Wt, int K, int N) {
  __shared__ float tile[32][33];
  int n0 = blockIdx.x * 32, k0 = blockIdx.y * 32;
  int t = threadIdx.x;
  int c = t & 31, r = t >> 5;
#pragma unroll
  for (int p = 0; p < 4; ++p)
    tile[r + 8 * p][c] = W[(size_t)(k0 + r + 8 * p) * N + n0 + c];
  __syncthreads();
#pragma unroll
  for (int p = 0; p < 4; ++p)
    Wt[(size_t)(n0 + r + 8 * p) * K + k0 + c] = f2bf(tile[c][r + 8 * p]);
}

// ---------------- bf16 MFMA GEMM: C = A(MxK) @ Bt(NxK)^T ----------------
// EPI: 1 = silu->bf16; 2 = Gate*acc->bf16 (in-place ok); 3 = Res+acc->f32;
//      4 = qkv split: cols<2048 -> bf16 Cb, cols>=2048 -> V transposed to VtP[b,h,d,s]
template<int EPI>
__global__ __launch_bounds__(256, 2) void gemm_mfma(
    const ushort* __restrict__ A, const ushort* __restrict__ Bt,
    const float* __restrict__ Res, const ushort* __restrict__ Gate,
    float* __restrict__ Cf, ushort* __restrict__ Cb, ushort* __restrict__ VtP,
    int M, int N, int K) {
  __shared__ ushort As[128 * 64];
  __shared__ ushort Bs[128 * 64];
  char* Au = (char*)As;
  char* Bu = (char*)Bs;
  int t = threadIdx.x;
  int bm = blockIdx.y * 128, bn = blockIdx.x * 128;
  int lane = t & 63, wid = t >> 6;
  int wr = wid >> 1, wc = wid & 1;
  int l15 = lane & 15, l4 = lane >> 4;
  int swz = l15 & 7;

  int ldsoff[4];
  const ushort* pA[4];
  const ushort* pB[4];
#pragma unroll
  for (int p = 0; p < 4; ++p) {
    int flat = p * 256 + t;
    int row = flat >> 3, slot = flat & 7;
    ldsoff[p] = row * 128 + ((slot ^ (row & 7)) << 4);
    pA[p] = A + (size_t)(bm + row) * K + slot * 8;
    pB[p] = Bt + (size_t)(bn + row) * K + slot * 8;
  }

  f32x4 acc[4][4];
#pragma unroll
  for (int m = 0; m < 4; ++m)
#pragma unroll
    for (int n = 0; n < 4; ++n) acc[m][n] = (f32x4){0.f, 0.f, 0.f, 0.f};

  uint4 ra[4], rb[4];
#pragma unroll
  for (int p = 0; p < 4; ++p) { ra[p] = *(const uint4*)pA[p]; rb[p] = *(const uint4*)pB[p]; }

  int nk = K >> 6;
  for (int kt = 0; kt < nk; ++kt) {
    __syncthreads();
#pragma unroll
    for (int p = 0; p < 4; ++p) {
      *(uint4*)(Au + ldsoff[p]) = ra[p];
      *(uint4*)(Bu + ldsoff[p]) = rb[p];
    }
    __syncthreads();
    if (kt + 1 < nk) {
#pragma unroll
      for (int p = 0; p < 4; ++p) {
        pA[p] += 64; pB[p] += 64;
        ra[p] = *(const uint4*)pA[p];
        rb[p] = *(const uint4*)pB[p];
      }
    }
#pragma unroll
    for (int kk = 0; kk < 2; ++kk) {
      int tslot = ((kk * 4 + l4) ^ swz) << 4;
      short8 a[4], b[4];
#pragma unroll
      for (int i = 0; i < 4; ++i) {
        int arow = wr * 64 + i * 16 + l15;
        int brow = wc * 64 + i * 16 + l15;
        a[i] = *(const short8*)(Au + arow * 128 + tslot);
        b[i] = *(const short8*)(Bu + brow * 128 + tslot);
      }
#pragma unroll
      for (int m = 0; m < 4; ++m)
#pragma unroll
        for (int n = 0; n < 4; ++n)
          acc[m][n] = __builtin_amdgcn_mfma_f32_16x16x32_bf16(a[m], b[n], acc[m][n], 0, 0, 0);
    }
  }

#pragma unroll
  for (int m = 0; m < 4; ++m) {
#pragma unroll
    for (int n = 0; n < 4; ++n) {
      int row0 = bm + wr * 64 + m * 16 + l4 * 4;
      int col  = bn + wc * 64 + n * 16 + l15;
      if constexpr (EPI == 4) {
        if (bn >= 2048) {
          int vc = col - 2048, hh = vc >> 6, dd = vc & 63;
          int bbv = row0 >> 11, s0 = row0 & 2047;
          bf4 pk4;
          pk4.a = f2bf(acc[m][n][0]); pk4.b = f2bf(acc[m][n][1]);
          pk4.c = f2bf(acc[m][n][2]); pk4.d = f2bf(acc[m][n][3]);
          *(bf4*)(VtP + ((((size_t)bbv * 16 + hh) * 64 + dd) << 11) + s0) = pk4;
        } else {
#pragma unroll
          for (int j = 0; j < 4; ++j)
            Cb[(size_t)(row0 + j) * N + col] = f2bf(acc[m][n][j]);
        }
      } else {
#pragma unroll
        for (int j = 0; j < 4; ++j) {
          float v = acc[m][n][j];
          size_t idx = (size_t)(row0 + j) * (size_t)N + col;
          if constexpr (EPI == 1) {
            Cb[idx] = f2bf(v / (1.f + __expf(-v)));
          } else if constexpr (EPI == 2) {
            Cb[idx] = f2bf(bf2f(Gate[idx]) * v);
          } else {
            Cf[idx] = Res[idx] + v;
          }
        }
      }
    }
  }
}

// ---------------- MFMA causal flash attention ----------------
// 4 waves x 32 q-rows. Swapped QK^T (mfma(K,Q) -> S^T, col=lane&31=qrow).
// K, Vt staged in LDS with row-XOR swizzle; P redistributed to A-fragments
// via pack + shfl_xor(32); defer-max online softmax in log2 domain.
__global__ __launch_bounds__(256, 2) void attn_mfma_kernel(
    const ushort* __restrict__ qkv,   // [B*S][3072] bf16 (Q at 0, K at 1024)
    const ushort* __restrict__ Vt,    // [B*H][64][2048] bf16
    ushort* __restrict__ AO) {        // [B*S][1024] bf16
  __shared__ ushort lds[8192];        // K [0,4096), Vt [4096,8192); reused as Obuf
  const float SL2 = 0.125f * 1.44269504f;   // scale * log2(e)
  int t = threadIdx.x;
  int x = blockIdx.x;
  int second = x >> 8;
  int pair = x & 255;
  int h = pair & 15;
  int bb = (pair >> 4) & 1;
  int qt3 = (pair >> 5) & 7;
  int qt = second ? (15 - qt3) : qt3;
  int q0 = qt * 128;
  int lane = t & 63, wv = t >> 6;
  int l31 = lane & 31, g = lane >> 5;

  // Q fragments: lane holds Q[qrow=l31][d = 16s + 8g + j]
  const ushort* qrow_ptr = qkv + (size_t)(bb * S_ + q0 + wv * 32 + l31) * 3072 + h * 64;
  short8 qf[4];
#pragma unroll
  for (int s = 0; s < 4; ++s) qf[s] = *(const short8*)(qrow_ptr + s * 16 + g * 8);

  f32x16 accO[2];
#pragma unroll
  for (int u = 0; u < 2; ++u)
#pragma unroll
    for (int r = 0; r < 16; ++r) accO[u][r] = 0.f;
  float m = -INFINITY, l = 0.f;
  int qg = q0 + wv * 32 + l31;      // this lane's q-row
  int qmin = q0 + wv * 32, qmax = qmin + 31;
  int ntiles = (q0 + 128) >> 6;

  const ushort* kbase = qkv + (size_t)(bb * S_) * 3072 + 1024 + h * 64;
  const ushort* vbase = Vt + ((size_t)(bb * 16 + h) * 64) * 2048;

  for (int kti = 0; kti < ntiles; ++kti) {
    int kt = kti << 6;
    __syncthreads();
#pragma unroll
    for (int p = 0; p < 2; ++p) {
      int flat = p * 256 + t;
      int row = flat >> 3, slot = flat & 7;
      *(short8*)&lds[row * 64 + ((slot ^ (row & 7)) << 3)] =
          *(const short8*)(kbase + (size_t)(kt + row) * 3072 + slot * 8);
      *(short8*)&lds[4096 + row * 64 + ((slot ^ (row & 7)) << 3)] =
          *(const short8*)(vbase + (size_t)row * 2048 + kt + slot * 8);
    }
    __syncthreads();
    if (kt > qmax) continue;

    // QK^T (swapped): accT[t2] col = qrow, row = key_local
    f32x16 accT[2];
#pragma unroll
    for (int t2 = 0; t2 < 2; ++t2)
#pragma unroll
      for (int r = 0; r < 16; ++r) accT[t2][r] = 0.f;
#pragma unroll
    for (int t2 = 0; t2 < 2; ++t2) {
      int key = 32 * t2 + l31;
#pragma unroll
      for (int s = 0; s < 4; ++s) {
        short8 kf = *(const short8*)&lds[key * 64 + (((2 * s + g) ^ (key & 7)) << 3)];
        accT[t2] = __builtin_amdgcn_mfma_f32_32x32x16_bf16(kf, qf[s], accT[t2], 0, 0, 0);
      }
    }

    // masked scores in log2 domain
    bool need_mask = (kt + 63 > qmin);
    float p_[2][16];
    float pmax = -INFINITY;
#pragma unroll
    for (int t2 = 0; t2 < 2; ++t2)
#pragma unroll
      for (int r = 0; r < 16; ++r) {
        float v = accT[t2][r] * SL2;
        if (need_mask) {
          int key = kt + 32 * t2 + (r & 3) + 8 * (r >> 2) + 4 * g;
          if (key > qg) v = -INFINITY;
        }
        p_[t2][r] = v;
        pmax = fmaxf(pmax, v);
      }
    pmax = fmaxf(pmax, __shfl_xor(pmax, 32));

    if (__any(pmax > m + 11.5f)) {    // defer-max, THR = 8 nats
      float mnew = fmaxf(m, pmax);
      float corr = exp2f(m - mnew);   // m=-inf -> 0
      m = mnew;
      l *= corr;
      float cr[16];
#pragma unroll
      for (int r = 0; r < 16; ++r) cr[r] = __shfl(corr, (r & 3) + 8 * (r >> 2) + 4 * g);
#pragma unroll
      for (int r = 0; r < 16; ++r) { accO[0][r] *= cr[r]; accO[1][r] *= cr[r]; }
    }
    float psum = 0.f;
#pragma unroll
    for (int t2 = 0; t2 < 2; ++t2)
#pragma unroll
      for (int r = 0; r < 16; ++r) {
        float e = exp2f(p_[t2][r] - m);
        p_[t2][r] = e;
        psum += e;
      }
    psum += __shfl_xor(psum, 32);
    l += psum;

    // build P A-fragments (redistribute g-halves) + PV
#pragma unroll
    for (int s = 0; s < 4; ++s) {
      int ca = 2 * s, cb2 = 2 * s + 1;
      int ta = ca >> 2, ra = (ca & 3) * 4;
      int tb = cb2 >> 2, rbq = (cb2 & 3) * 4;
      unsigned w0a = pk2(p_[ta][ra], p_[ta][ra + 1]);
      unsigned w1a = pk2(p_[ta][ra + 2], p_[ta][ra + 3]);
      unsigned w0b = pk2(p_[tb][rbq], p_[tb][rbq + 1]);
      unsigned w1b = pk2(p_[tb][rbq + 2], p_[tb][rbq + 3]);
      unsigned x0a = __shfl_xor(w0a, 32), x1a = __shfl_xor(w1a, 32);
      unsigned x0b = __shfl_xor(w0b, 32), x1b = __shfl_xor(w1b, 32);
      union { unsigned u[4]; short8 s8; } pa;
      pa.u[0] = g ? x0b : w0a;
      pa.u[1] = g ? x1b : w1a;
      pa.u[2] = g ? w0b : x0a;
      pa.u[3] = g ? w1b : x1a;
#pragma unroll
      for (int u = 0; u < 2; ++u) {
        int d = 32 * u + l31;
        short8 vf = *(const short8*)&lds[4096 + d * 64 + (((2 * s + g) ^ (d & 7)) << 3)];
        accO[u] = __builtin_amdgcn_mfma_f32_32x32x16_bf16(pa.s8, vf, accO[u], 0, 0, 0);
      }
    }
  }

  // epilogue: normalize, stage to LDS, coalesced store
  float linv = 1.f / l;
  float lr[16];
#pragma unroll
  for (int r = 0; r < 16; ++r) lr[r] = __shfl(linv, (r & 3) + 8 * (r >> 2) + 4 * g);
  __syncthreads();
#pragma unroll
  for (int r = 0; r < 16; ++r) {
    int row = wv * 32 + (r & 3) + 8 * (r >> 2) + 4 * g;
    lds[row * 64 + l31]      = f2bf(accO[0][r] * lr[r]);
    lds[row * 64 + 32 + l31] = f2bf(accO[1][r] * lr[r]);
  }
  __syncthreads();
#pragma unroll
  for (int p = 0; p < 4; ++p) {
    int flat = p * 256 + t;
    int row = flat >> 3, slot = flat & 7;
    *(short8*)(AO + (size_t)(bb * S_ + q0 + row) * 1024 + h * 64 + slot * 8) =
        *(const short8*)&lds[row * 64 + slot * 8];
  }
}

// ---------------- column mean over S (two stage) ----------------
__global__ void colmean1(const float* __restrict__ X, float* __restrict__ part) {
  int d = blockIdx.x * 256 + threadIdx.x;
  int b = blockIdx.y;
  int ch = blockIdx.z;
  float s = 0.f;
  int s0 = ch * (S_ / 16);
  for (int i = 0; i < S_ / 16; ++i)
    s += X[(size_t)(b * S_ + s0 + i) * D_ + d];
  part[(b * 16 + ch) * D_ + d] = s;
}
__global__ void colmean2(const float* __restrict__ part, float* __restrict__ cm) {
  int d = blockIdx.x * 256 + threadIdx.x;
  int b = blockIdx.y;
  float s = 0.f;
#pragma unroll
  for (int c = 0; c < 16; ++c) s += part[(b * 16 + c) * D_ + d];
  cm[b * D_ + d] = s * (1.f / (float)S_);
}

// ---------------- recurrent state update ----------------
__global__ __launch_bounds__(128) void state_kernel(
    const float* __restrict__ cm, const float* __restrict__ state,
    const float* __restrict__ w_h2s, const float* __restrict__ w_sg,
    float* __restrict__ out_tail) {
  int t = threadIdx.x;
  int b = t >> 6, j = t & 63;
  float ni = 0.f;
  for (int k = 0; k < D_; ++k) ni += cm[b * D_ + k] * w_h2s[k * SD_ + j];
  __shared__ float ni_s[128];
  ni_s[t] = ni;
  __syncthreads();
  float g = 0.f;
#pragma unroll
  for (int k = 0; k < SD_; ++k) g += state[b * SD_ + k] * w_sg[k * SD_ + j];
#pragma unroll
  for (int k = 0; k < SD_; ++k) g += ni_s[b * SD_ + k] * w_sg[(SD_ + k) * SD_ + j];
  g = 1.f / (1.f + __expf(-g));
  float st = state[b * SD_ + j];
  out_tail[b * SD_ + j] = st * (1.f - g) + ni * g;
}

extern "C" void kernel_launch(void* const* d_in, const int* in_sizes, int n_in,
                              void* d_out, int out_size, void* d_ws, size_t ws_size,
                              hipStream_t stream) {
  const float* x      = (const float*)d_in[0];
  const float* gamma  = (const float*)d_in[1];
  const float* beta   = (const float*)d_in[2];
  const float* state  = (const float*)d_in[3];
  const float* w_qkv  = (const float*)d_in[4];
  const float* w_o    = (const float*)d_in[5];
  const float* w_gate = (const float*)d_in[6];
  const float* w_up   = (const float*)d_in[7];
  const float* w_down = (const float*)d_in[8];
  const float* norm1w = (const float*)d_in[9];
  const float* norm2w = (const float*)d_in[10];
  const float* w_sm   = (const float*)d_in[11];
  const float* w_h2s  = (const float*)d_in[12];
  const float* w_sg   = (const float*)d_in[13];
  float* out = (float*)d_out;

  float* ws = (float*)d_ws;
  float*  fg     = ws;                         // 2048
  float*  fb     = ws + 2048;                  // 2048
  float*  cm     = ws + 4096;                  // 2048
  float*  part   = ws + 8192;                  // 32768
  ushort* h_bf   = (ushort*)(ws + 65536);                               // M*D bf16
  ushort* AO_bf  = (ushort*)(ws + 65536 + 2097152);                     // M*D bf16
  ushort* wT     = (ushort*)(ws + 65536 + 2 * 2097152);                 // <=3072x1024 bf16
  ushort* qkv_bf = (ushort*)(ws + 65536 + 2 * 2097152 + 1572864);       // M*3D bf16
  ushort* Vt_g   = (ushort*)(ws + 65536 + 2 * 2097152 + 1572864 + 6291456);  // B*H*64*S bf16
  ushort* gate_bf = qkv_bf;   // reuses qkv slot (dead after attention)

  // 1. FiLM params
  film_kernel<<<dim3(8, B_), 256, 0, stream>>>(state, w_sm, gamma, beta, fg, fb);
  // 2. h = rmsnorm(x,norm1)*fg + fb  -> bf16
  rmsnorm_film_kernel<<<M_, 256, 0, stream>>>(x, norm1w, fg, fb, h_bf);
  // 3. qkv = h @ w_qkv  -> Q/K bf16 + V transposed
  transpose_bf16<<<dim3(D3_ / 32, D_ / 32), 256, 0, stream>>>(w_qkv, wT, D_, D3_);
  gemm_mfma<4><<<dim3(D3_ / 128, M_ / 128), 256, 0, stream>>>(
      h_bf, wT, nullptr, nullptr, nullptr, qkv_bf, Vt_g, M_, D3_, D_);
  // 4. attention -> AO bf16
  attn_mfma_kernel<<<512, 256, 0, stream>>>(qkv_bf, Vt_g, AO_bf);
  // 5. x1 = x + AO @ w_o -> d_out
  transpose_bf16<<<dim3(D_ / 32, D_ / 32), 256, 0, stream>>>(w_o, wT, D_, D_);
  gemm_mfma<3><<<dim3(D_ / 128, M_ / 128), 256, 0, stream>>>(
      AO_bf, wT, x, nullptr, out, nullptr, nullptr, M_, D_, D_);
  // 6. h2 = rmsnorm(x1,norm2)*fg + fb -> bf16
  rmsnorm_film_kernel<<<M_, 256, 0, stream>>>(out, norm2w, fg, fb, h_bf);
  // 7. gate = silu(h2 @ w_gate) -> bf16 (qkv slot)
  transpose_bf16<<<dim3(D3_ / 32, D_ / 32), 256, 0, stream>>>(w_gate, wT, D_, D3_);
  gemm_mfma<1><<<dim3(D3_ / 128, M_ / 128), 256, 0, stream>>>(
      h_bf, wT, nullptr, nullptr, nullptr, gate_bf, nullptr, M_, D3_, D_);
  // 8. gu = gate * (h2 @ w_up) -> in-place into gate buffer
  transpose_bf16<<<dim3(D3_ / 32, D_ / 32), 256, 0, stream>>>(w_up, wT, D_, D3_);
  gemm_mfma<2><<<dim3(D3_ / 128, M_ / 128), 256, 0, stream>>>(
      h_bf, wT, nullptr, gate_bf, nullptr, gate_bf, nullptr, M_, D3_, D_);
  // 9. x2 = x1 + gu @ w_down -> d_out
  transpose_bf16<<<dim3(D_ / 32, D3_ / 32), 256, 0, stream>>>(w_down, wT, D3_, D_);
  gemm_mfma<3><<<dim3(D_ / 128, M_ / 128), 256, 0, stream>>>(
      gate_bf, wT, out, nullptr, out, nullptr, nullptr, M_, D_, D3_);
  // 10. column mean over S
  colmean1<<<dim3(4, B_, 16), 256, 0, stream>>>(out, part);
  colmean2<<<dim3(4, B_), 256, 0, stream>>>(part, cm);
  // 11. state update -> tail of d_out
  state_kernel<<<1, 128, 0, stream>>>(cm, state, w_h2s, w_sg, out + (size_t)M_ * D_);
}